// Round 9
// baseline (247.044 us; speedup 1.0000x reference)
//
#include <hip/hip_runtime.h>

// out[b,j,hw] = exp( sum_i log(relu(x[b,i,hw])+0.1) * E[i,j] ) + bias[j]
// x: (B=32, NC=64, H=128, W=128) fp32.
//
// R11: CHUNK-SIZE experiment. R10 (global_load_lds + counted vmcnt + dbuf,
// conflict-free) = 86.8us == R6/R8/R9 == ~2.4 TB/s. Same profile shows
// fillBufferAligned hitting 6.1-6.3 TB/s (537MB seq writes, 9% occupancy):
// the machine streams fine; OUR pattern doesn't. Every structure so far
// reads/writes 256-512B chunks at 64KB plane stride; 256B->512B moved BW
// 2.0->2.4 TB/s. Hypothesis: DRAM page efficiency on short strided bursts.
// Test: 2KB chunks (TPTS=512), the max LDS allows, everything else as R10:
//   - lxs[64][512] fp32 = 128KB static LDS (m201 precedent), 512 thr/blk,
//     1 blk/CU; half-tile (256pt) ping-pong, stage 8x1KB instr/wave/half.
//   - ALL waits are vmcnt(8): stages & stores alternate in batches of 8,
//     in-order retirement makes every "half ready" wait = vmcnt(8). Never 0.
//   - restage of a half sits AFTER the barrier proving its readers done.
//   - swizzle/log/hi-lo-split/MFMA/store numerics IDENTICAL to R10
//     (passed, absmax 0.015625). Per-CU in-flight ~64KB unchanged ->
//     chunk size is the isolated variable.
// Success: hbm >=3800 GB/s, dur 50-62us. Failure (85-90us): chunk size
// exonerated -> pattern-fundamental cap; restructure output or ceiling.
#define NCH 64
#define HWSZ 16384
#define NPOINTS (32 * HWSZ)      // 524288
#define TPTS 512                 // points per tile (2KB/plane chunks)
#define NTILES (NPOINTS / TPTS)  // 1024
#define NBLK 512                 // 2 tiles per block
#define HPTS 256                 // points per half-tile

typedef __attribute__((ext_vector_type(8))) short bf16x8;  // 8 bf16, 4 VGPRs
typedef __attribute__((ext_vector_type(4))) float f32x4;

union fragU { bf16x8 v; unsigned int u[4]; };

static __device__ __forceinline__ unsigned int fbits(float f) {
    return __float_as_uint(f);
}
static __device__ __forceinline__ float bfup(unsigned int b) {
    return __uint_as_float(b & 0xFFFF0000u);
}

__global__ __launch_bounds__(512, 2) void fused_log_einsum_exp(
    const float* __restrict__ x,
    const float* __restrict__ E,     // (64,64) row-major: E[i*64+j]
    const float* __restrict__ bias,  // (64)
    float* __restrict__ out)
{
    __shared__ float lxs[NCH][TPTS];   // 64 x 512 x 4B = 128 KB

    const int lane = threadIdx.x & 63;
    const int wv   = threadIdx.x >> 6;   // wave 0..7
    const int lg   = lane >> 4;          // 0..3
    const int ln   = lane & 15;          // 0..15

    // ---- B-frags: E row-major (k=i, col=j), hi-only (entries bf16-exact).
    // B: lane l holds B[k=(l>>4)*8+e][col=l&15].
    bf16x8 bE[4][2];
    #pragma unroll
    for (int m = 0; m < 4; ++m) {
        #pragma unroll
        for (int kk = 0; kk < 2; ++kk) {
            fragU h;
            #pragma unroll
            for (int w = 0; w < 4; ++w) {
                const int i0 = kk * 32 + lg * 8 + 2 * w;
                const int j  = m * 16 + ln;
                h.u[w] = (fbits(E[(i0 + 1) * NCH + j]) & 0xFFFF0000u)
                       | (fbits(E[i0 * NCH + j]) >> 16);
            }
            bE[m][kk] = h.v;
        }
    }
    float bj[4];
    #pragma unroll
    for (int m = 0; m < 4; ++m) bj[m] = bias[m * 16 + ln];

// float-index base of tile T (pt0 = T*512; 512 | HWSZ -> never crosses b)
#define TILE_PB(T) ((size_t)(((T) * TPTS) & ~(HWSZ - 1)) * NCH \
                  + (size_t)(((T) * TPTS) & (HWSZ - 1)))

// Stage half H of tile T: wave wv covers planes [wv*8, wv*8+8), one 1KB
// global_load_lds per plane (64 lanes x 16B, contiguous). Source pre-XOR'd
// at 16-float granularity (sw = ((p>>3)&1)<<4), LDS dest linear (G21);
// read side applies the same XOR -> 2-way banks = free (R10-verified).
#define STAGE(H, T) do {                                                       \
    const size_t pb_ = TILE_PB(T);                                             \
    _Pragma("unroll")                                                          \
    for (int n_ = 0; n_ < 8; ++n_) {                                           \
        const int p_  = wv * 8 + n_;                                           \
        const int sw_ = ((p_ >> 3) & 1) << 4;                                  \
        const size_t g_ = pb_ + (size_t)p_ * HWSZ + (H) * HPTS                 \
                        + (size_t)((lane * 4) ^ sw_);                          \
        __builtin_amdgcn_global_load_lds(                                      \
            (const __attribute__((address_space(1))) unsigned int*)(x + g_),   \
            (__attribute__((address_space(3))) unsigned int*)&lxs[p_][(H) * HPTS],\
            16, 0, 0);                                                         \
    }                                                                          \
} while (0)

// Compute half H of tile T: wave wv owns pts H*256 + [wv*32, wv*32+32) =
// 2 MFMA-subs. A: lane holds A[row=pt=ln][k=lg*8+e] from swizzled ds_reads,
// lx split hi/lo (real precision bits); B=E; D: lane,reg r -> [pt=lg*4+r]
// [j=m*16+ln] => float4 stores, 8 per wave per half.
#define COMPUTE(H, T) do {                                                     \
    const size_t po_ = TILE_PB(T);                                             \
    _Pragma("unroll")                                                          \
    for (int sub_ = 0; sub_ < 2; ++sub_) {                                     \
        const int pq_ = (H) * HPTS + wv * 32 + sub_ * 16 + ln;                 \
        fragU ah_[2], al_[2];                                                  \
        _Pragma("unroll")                                                      \
        for (int kk_ = 0; kk_ < 2; ++kk_) {                                    \
            _Pragma("unroll")                                                  \
            for (int w_ = 0; w_ < 4; ++w_) {                                   \
                const int i0_ = kk_ * 32 + lg * 8 + 2 * w_;                    \
                const int sw_ = ((i0_ >> 3) & 1) << 4;   /* same for i0_+1 */  \
                const float v0_ = lxs[i0_][pq_ ^ sw_];                         \
                const float v1_ = lxs[i0_ + 1][pq_ ^ sw_];                     \
                const float a0_ = __logf(fmaxf(v0_, 0.0f) + 0.1f);             \
                const float a1_ = __logf(fmaxf(v1_, 0.0f) + 0.1f);             \
                ah_[kk_].u[w_] = (fbits(a1_) & 0xFFFF0000u) | (fbits(a0_) >> 16); \
                const float b0_ = a0_ - bfup(fbits(a0_));                      \
                const float b1_ = a1_ - bfup(fbits(a1_));                      \
                al_[kk_].u[w_] = (fbits(b1_) & 0xFFFF0000u) | (fbits(b0_) >> 16); \
            }                                                                  \
        }                                                                      \
        _Pragma("unroll")                                                      \
        for (int m_ = 0; m_ < 4; ++m_) {                                       \
            f32x4 acc_ = {0.f, 0.f, 0.f, 0.f};                                 \
            _Pragma("unroll")                                                  \
            for (int kk_ = 0; kk_ < 2; ++kk_) {                                \
                acc_ = __builtin_amdgcn_mfma_f32_16x16x32_bf16(                \
                           ah_[kk_].v, bE[m_][kk_], acc_, 0, 0, 0);            \
                acc_ = __builtin_amdgcn_mfma_f32_16x16x32_bf16(                \
                           al_[kk_].v, bE[m_][kk_], acc_, 0, 0, 0);            \
            }                                                                  \
            float4 o_;                                                         \
            o_.x = __expf(acc_[0]) + bj[m_];                                   \
            o_.y = __expf(acc_[1]) + bj[m_];                                   \
            o_.z = __expf(acc_[2]) + bj[m_];                                   \
            o_.w = __expf(acc_[3]) + bj[m_];                                   \
            *reinterpret_cast<float4*>(out + po_                               \
                + (size_t)(m_ * 16 + ln) * HWSZ                                \
                + (size_t)((H) * HPTS + wv * 32 + sub_ * 16 + lg * 4)) = o_;   \
        }                                                                      \
    }                                                                          \
} while (0)

#define WAIT8_BARRIER do {                                                     \
    asm volatile("s_waitcnt vmcnt(8)" ::: "memory");                           \
    __builtin_amdgcn_s_barrier();                                              \
    __builtin_amdgcn_sched_barrier(0);                                         \
} while (0)

    const int t0 = (int)blockIdx.x;        // tile 0
    const int t1 = t0 + NBLK;              // tile 1

    // Per-wave vmem issue order (batches of 8, in-order retirement):
    //   H0(t0) H1(t0) | st(H0,t0) H0(t1) | st(H1,t0) H1(t1) | st(H0,t1) ...
    // => every "half ready" wait is exactly vmcnt(8). Never 0: the next
    // half's loads (or this half's stores) always stay in flight.
    STAGE(0, t0);
    STAGE(1, t0);
    WAIT8_BARRIER;            // H0(t0) landed; H1(t0) in flight
    COMPUTE(0, t0);
    WAIT8_BARRIER;            // H1(t0) landed; readers of H0(t0) all done
    STAGE(0, t1);             // restage H0 under COMPUTE(H1)
    COMPUTE(1, t0);
    WAIT8_BARRIER;            // H0(t1) landed; readers of H1(t0) all done
    STAGE(1, t1);             // restage H1 under COMPUTE(H0)
    COMPUTE(0, t1);
    WAIT8_BARRIER;            // H1(t1) landed
    COMPUTE(1, t1);           // final stores drain at kernel end

#undef TILE_PB
#undef STAGE
#undef COMPUTE
#undef WAIT8_BARRIER
}

extern "C" void kernel_launch(void* const* d_in, const int* in_sizes, int n_in,
                              void* d_out, int out_size, void* d_ws, size_t ws_size,
                              hipStream_t stream) {
    const float* x    = (const float*)d_in[0];
    const float* E    = (const float*)d_in[1];   // (64,64,1,1) -> [i*64+j]
    const float* bias = (const float*)d_in[2];   // (64,1,1)
    float* out = (float*)d_out;

    dim3 grid(NBLK), block(512);
    hipLaunchKernelGGL(fused_log_einsum_exp, grid, block, 0, stream,
                       x, E, bias, out);
}